// Round 10
// baseline (114.452 us; speedup 1.0000x reference)
//
#include <hip/hip_runtime.h>
#include <math.h>

#define NEXP 8
#define DIN 128
#define ISZ 16
#define TT 8                       // tokens per wave
#define NWAVE 4
#define TOK_PER_BLK (TT * NWAVE)   // 32
#define NTOK (16 * 4096)           // 65536

typedef float f32x4 __attribute__((ext_vector_type(4)));
typedef unsigned int u32;
typedef u32 u32x4 __attribute__((ext_vector_type(4)));

#define LDS_W2_U32 8192            // w2 as bf16 row-pairs: 8e*8i2*128c u32 = 32 KB
#define LDS_GY_F32 (TOK_PER_BLK * DIN)   // 16 KB
#define SMEM_BYTES (LDS_W2_U32 * 4 + LDS_GY_F32 * 4)   // 48 KB

__device__ __forceinline__ u32 pack_bf16(float lo, float hi) {
    u32 a = (__float_as_uint(lo) + 0x8000u) >> 16;          // round-half-up bf16
    u32 b = (__float_as_uint(hi) + 0x8000u) & 0xffff0000u;
    return b | a;
}
__device__ __forceinline__ float bf_lo(u32 v) { return __uint_as_float(v << 16); }
__device__ __forceinline__ float bf_hi(u32 v) { return __uint_as_float(v & 0xffff0000u); }

// ---- pack w1 [e][c][i] into lane-major bf16-pair P ----
// P[c4*256 + lane*4 + k] = pack( w1[e][4c4+k][2g], w1[e][4c4+k][2g+1] ), lane=e*8+g
// GEMM1: lane loads ONE u32x4 per c4 (16B) covering its 8 weights.
__global__ void pack_w1_kernel(const float* __restrict__ w1, u32* __restrict__ P) {
    int idx = blockIdx.x * 256 + threadIdx.x;       // 0 .. 8191
    int c4 = idx >> 8;
    int r  = idx & 255;
    int ln = r >> 2;
    int k  = r & 3;
    int e  = ln >> 3;
    int g  = ln & 7;
    const float* src = w1 + e * 2048 + (4 * c4 + k) * 16 + 2 * g;
    P[idx] = pack_bf16(src[0], src[1]);
}

__global__ __launch_bounds__(256, 1) __attribute__((amdgpu_num_vgpr(128)))
void moe_fused_kernel(
    const float* __restrict__ x,
    const float* __restrict__ rw,
    const u32*   __restrict__ P,     // packed bf16 w1 in d_ws
    const float* __restrict__ w2,
    float* __restrict__ out_agg,
    float* __restrict__ out_exp)
{
    extern __shared__ u32 ldsu[];
    u32*   w2L = ldsu;                         // [e][i2][c] bf16 pair (rows 2i2,2i2+1)
    float* gys = (float*)(ldsu + LDS_W2_U32);  // [32 tok][128] gelu(y)

    const int tid  = threadIdx.x;
    const int wave = tid >> 6;
    const int lane = tid & 63;
    const int btok = blockIdx.x * TOK_PER_BLK;
    const int wtok = btok + wave * TT;

    // ---- stage w2 into LDS as bf16 row-pairs (coalesced f32x4 reads) ----
#pragma unroll
    for (int jj = 0; jj < 8; ++jj) {
        int j  = tid + jj * 256;               // 0 .. 2047 (u32x4 groups)
        int e  = j >> 8;
        int i2 = (j >> 5) & 7;
        int c4 = j & 31;
        const float* base = w2 + e * 2048 + (2 * i2) * 128 + c4 * 4;
        f32x4 lo4 = *(const f32x4*)base;           // row 2*i2
        f32x4 hi4 = *(const f32x4*)(base + 128);   // row 2*i2+1
        u32x4 p;
        p.x = pack_bf16(lo4.x, hi4.x);
        p.y = pack_bf16(lo4.y, hi4.y);
        p.z = pack_bf16(lo4.z, hi4.z);
        p.w = pack_bf16(lo4.w, hi4.w);
        *(u32x4*)(w2L + j * 4) = p;
    }
    __syncthreads();

    float* gyw = gys + wave * TT * DIN;        // wave-private gy slice

    // ================= GEMM1: y[t][e][i] = x . w1 =================
    // lane -> (e1 = lane>>3, g = lane&7); computes i = 2g, 2g+1 for 8 tokens.
    const int e1 = lane >> 3;
    const int g  = lane & 7;

    float y0[TT], y1[TT];
#pragma unroll
    for (int t = 0; t < TT; ++t) { y0[t] = 0.f; y1[t] = 0.f; }

    const u32* Pl = P + lane * 4;
    const int xoff = __builtin_amdgcn_readfirstlane(wtok * DIN);
    const float* xu = x + xoff;                // wave-uniform base -> scalar loads

#pragma unroll 1
    for (int c4 = 0; c4 < 32; ++c4) {
        u32x4 u = *(const u32x4*)(Pl + c4 * 256);
        float wa0 = bf_lo(u.x), wb0 = bf_hi(u.x);
        float wa1 = bf_lo(u.y), wb1 = bf_hi(u.y);
        float wa2 = bf_lo(u.z), wb2 = bf_hi(u.z);
        float wa3 = bf_lo(u.w), wb3 = bf_hi(u.w);
#pragma unroll
        for (int t = 0; t < TT; ++t) {
            float x0 = xu[t * DIN + c4 * 4 + 0];   // uniform -> scalar pipe
            float x1 = xu[t * DIN + c4 * 4 + 1];
            float x2 = xu[t * DIN + c4 * 4 + 2];
            float x3 = xu[t * DIN + c4 * 4 + 3];
            y0[t] += x0 * wa0 + x1 * wa1 + x2 * wa2 + x3 * wa3;
            y1[t] += x0 * wb0 + x1 * wb1 + x2 * wb2 + x3 * wb3;
        }
    }

    // ---- exact GELU -> wave-private LDS slice (same-wave consumer, no barrier) ----
#pragma unroll
    for (int t = 0; t < TT; ++t) {
        float a = y0[t], b = y1[t];
        a = 0.5f * a * (1.f + erff(a * 0.70710678118654752f));
        b = 0.5f * b * (1.f + erff(b * 0.70710678118654752f));
        *(float2*)(gyw + t * DIN + e1 * ISZ + 2 * g) = make_float2(a, b);
    }

    // ================= GEMM2 (w2 from LDS bf16) + weighted agg =================
    // lane -> q = lane&31 (channel quad), h = lane>>5 (expert parity)
    const int q = lane & 31;
    const int h = lane >> 5;
    const int c4s = q * 4;
    const u32* w2h = w2L + h * 1024 + q * 4;   // expert e=2k+h -> + k*2048
    const f32x4 vzero = (f32x4)(0.f);

#pragma unroll
    for (int th = 0; th < 2; ++th) {           // two 4-token halves
        f32x4 acc[4], agg[4];
#pragma unroll
        for (int t = 0; t < 4; ++t) { acc[t] = vzero; agg[t] = vzero; }

        // prime ch=0 (k=0, i4=0): row-pairs (0,1) and (2,3) of expert h
        u32x4 qA = *(const u32x4*)(w2h + 0);
        u32x4 qB = *(const u32x4*)(w2h + 128);

#pragma unroll 1
        for (int ch = 0; ch < 16; ++ch) {      // (k = ch>>2, i4 = ch&3)
            const int k  = ch >> 2;
            const int i4 = ch & 3;
            const int nch = (ch < 15) ? ch + 1 : 15;   // clamped prefetch
            const u32* nb = w2h + (nch >> 2) * 2048 + (nch & 3) * 256;
            u32x4 nA = *(const u32x4*)nb;
            u32x4 nB = *(const u32x4*)(nb + 128);

            // unpack rows 4*i4 .. 4*i4+3 (quad c4s) from bf16 pairs
            f32x4 w0r = {bf_lo(qA.x), bf_lo(qA.y), bf_lo(qA.z), bf_lo(qA.w)};
            f32x4 w1r = {bf_hi(qA.x), bf_hi(qA.y), bf_hi(qA.z), bf_hi(qA.w)};
            f32x4 w2r = {bf_lo(qB.x), bf_lo(qB.y), bf_lo(qB.z), bf_lo(qB.w)};
            f32x4 w3r = {bf_hi(qB.x), bf_hi(qB.y), bf_hi(qB.z), bf_hi(qB.w)};

            const int e = 2 * k + h;
#pragma unroll
            for (int t = 0; t < 4; ++t) {
                f32x4 gv = *(const f32x4*)(gyw + (th * 4 + t) * DIN + e * ISZ + i4 * 4);
                acc[t] += w0r * gv.x + w1r * gv.y + w2r * gv.z + w3r * gv.w;
            }

            if (i4 == 3) {   // expert e complete: store + weighted agg + reset
#pragma unroll
                for (int t = 0; t < 4; ++t) {
                    const int gtok = wtok + th * 4 + t;
                    __builtin_nontemporal_store(acc[t],
                        (f32x4*)(out_exp + (size_t)gtok * (NEXP * DIN) + e * DIN + c4s));
                    float r = rw[(size_t)gtok * NEXP + e];
                    agg[t] += r * acc[t];
                    acc[t] = vzero;
                }
            }
            qA = nA; qB = nB;
        }

        // combine expert parities: lane l (+) lane l^32, then lanes 0..31 write
#pragma unroll
        for (int t = 0; t < 4; ++t) {
            agg[t].x += __shfl_xor(agg[t].x, 32);
            agg[t].y += __shfl_xor(agg[t].y, 32);
            agg[t].z += __shfl_xor(agg[t].z, 32);
            agg[t].w += __shfl_xor(agg[t].w, 32);
        }
        if (h == 0) {
#pragma unroll
            for (int t = 0; t < 4; ++t) {
                const int gtok = wtok + th * 4 + t;
                __builtin_nontemporal_store(agg[t],
                    (f32x4*)(out_agg + (size_t)gtok * DIN + c4s));
            }
        }
    }
}

extern "C" void kernel_launch(void* const* d_in, const int* in_sizes, int n_in,
                              void* d_out, int out_size, void* d_ws, size_t ws_size,
                              hipStream_t stream) {
    const float* x  = (const float*)d_in[0];
    const float* rw = (const float*)d_in[1];
    const float* w1 = (const float*)d_in[2];
    const float* w2 = (const float*)d_in[3];

    float* out_agg = (float*)d_out;                  // [NTOK][128]
    float* out_exp = out_agg + (size_t)NTOK * DIN;   // [NTOK][8][128]
    u32* P = (u32*)d_ws;                             // 32 KB packed bf16 w1

    pack_w1_kernel<<<dim3(32), dim3(256), 0, stream>>>(w1, P);

    dim3 grid(NTOK / TOK_PER_BLK);   // 2048
    dim3 block(256);
    moe_fused_kernel<<<grid, block, SMEM_BYTES, stream>>>(
        x, rw, P, w2, out_agg, out_exp);
}